// Round 4
// baseline (483.130 us; speedup 1.0000x reference)
//
#include <hip/hip_runtime.h>
#include <math.h>

#define GN 50000
#define GE 800000
#define INF 128
#define OUTF 64
#define LRELU_ALPHA 0.2f

#define BUCK_SH 7                          // bucket = dst >> 7  (128 dsts/bucket)
#define BUCKW   128
#define NB      ((GN + BUCKW - 1) / BUCKW) // 391 buckets
#define CHUNK   4096                       // edges per chist/mscatter block
#define NCH     ((GE + CHUNK - 1) / CHUNK) // 196 chunks
#define ACC_STRIDE 65                      // [dl][j] pad: bank = (dl + j) % 32

// ---------------------------------------------------------------------------
// K0: zero the per-bucket edge counts (tiny).
// ---------------------------------------------------------------------------
__global__ __launch_bounds__(256) void k_zero(int* __restrict__ bcnt) {
    int i = blockIdx.x * 256 + threadIdx.x;
    if (i < NB) bcnt[i] = 0;
}

// ---------------------------------------------------------------------------
// K1: Wh = h @ W (N x 128 @ 128 x 64), fused s1 = Wh@a1, s2 = Wh@a2.
// (unchanged this round; LDS-read-bound ~35us, next round's target)
// ---------------------------------------------------------------------------
__global__ __launch_bounds__(256) void k_gemm(const float* __restrict__ h,
                                              const float* __restrict__ W,
                                              const float* __restrict__ a,
                                              float* __restrict__ Wh,
                                              float* __restrict__ s1,
                                              float* __restrict__ s2) {
    __shared__ __align__(16) float Wlds[INF * OUTF];  // 32 KB
    int t = threadIdx.x;
    for (int i = t * 4; i < INF * OUTF; i += 256 * 4) {
        *(float4*)&Wlds[i] = *(const float4*)&W[i];
    }
    __syncthreads();

    int node = blockIdx.x * 16 + (t >> 4);
    int jg   = (t & 15) * 4;
    if (node >= GN) return;

    const float4* h4 = (const float4*)&h[node * INF];
    float4 acc = {0.f, 0.f, 0.f, 0.f};
    #pragma unroll
    for (int k4 = 0; k4 < INF / 4; ++k4) {
        float4 hv = h4[k4];
        int k = k4 * 4;
        float4 w0 = *(float4*)&Wlds[(k + 0) * OUTF + jg];
        float4 w1 = *(float4*)&Wlds[(k + 1) * OUTF + jg];
        float4 w2 = *(float4*)&Wlds[(k + 2) * OUTF + jg];
        float4 w3 = *(float4*)&Wlds[(k + 3) * OUTF + jg];
        acc.x += hv.x * w0.x + hv.y * w1.x + hv.z * w2.x + hv.w * w3.x;
        acc.y += hv.x * w0.y + hv.y * w1.y + hv.z * w2.y + hv.w * w3.y;
        acc.z += hv.x * w0.z + hv.y * w1.z + hv.z * w2.z + hv.w * w3.z;
        acc.w += hv.x * w0.w + hv.y * w1.w + hv.z * w2.w + hv.w * w3.w;
    }
    *(float4*)&Wh[node * OUTF + jg] = acc;

    float p1 = acc.x * a[jg]        + acc.y * a[jg + 1]
             + acc.z * a[jg + 2]    + acc.w * a[jg + 3];
    float p2 = acc.x * a[OUTF + jg]     + acc.y * a[OUTF + jg + 1]
             + acc.z * a[OUTF + jg + 2] + acc.w * a[OUTF + jg + 3];
    #pragma unroll
    for (int off = 8; off >= 1; off >>= 1) {
        p1 += __shfl_down(p1, off, 16);
        p2 += __shfl_down(p2, off, 16);
    }
    if ((t & 15) == 0) {
        s1[node] = p1;
        s2[node] = p2;
    }
}

// ---------------------------------------------------------------------------
// K2: coarse histogram: per-block LDS hist of dst>>7 -> global bucket counts.
// ---------------------------------------------------------------------------
__global__ __launch_bounds__(256) void k_chist(const int* __restrict__ dst,
                                               int* __restrict__ bcnt) {
    __shared__ int hist[NB];
    int t = threadIdx.x;
    for (int i = t; i < NB; i += 256) hist[i] = 0;
    __syncthreads();
    int base = blockIdx.x * CHUNK;
    #pragma unroll
    for (int i = 0; i < CHUNK / 256; ++i) {
        int e = base + i * 256 + t;
        if (e < GE) atomicAdd(&hist[dst[e] >> BUCK_SH], 1);
    }
    __syncthreads();
    for (int i = t; i < NB; i += 256) {
        int c = hist[i];
        if (c > 0) atomicAdd(&bcnt[i], c);
    }
}

// ---------------------------------------------------------------------------
// K3: single tiny block: exclusive scan of 391 bucket counts -> base, cursor.
// ---------------------------------------------------------------------------
__global__ __launch_bounds__(512) void k_scan(const int* __restrict__ bcnt,
                                              int* __restrict__ bbase,
                                              int* __restrict__ cursor) {
    __shared__ int lds[512];
    int t = threadIdx.x;
    int v = (t < NB) ? bcnt[t] : 0;
    lds[t] = v;
    __syncthreads();
    #pragma unroll
    for (int off = 1; off < 512; off <<= 1) {
        int u = (t >= off) ? lds[t - off] : 0;
        __syncthreads();
        lds[t] += u;
        __syncthreads();
    }
    if (t < NB) {
        int b = lds[t] - v;   // exclusive
        bbase[t]  = b;
        cursor[t] = b;
    }
}

// ---------------------------------------------------------------------------
// K4: multisplit scatter. Each block reserves ONE contiguous run per bucket
// (global atomic on cursor), then fills it via LDS cursors -> writebacks are
// near-full-line instead of 4B/line. After this, cursor[b] == end of bucket b.
// Payload: (src << 7) | (dst & 127).
// ---------------------------------------------------------------------------
__global__ __launch_bounds__(256) void k_mscatter(const int* __restrict__ src,
                                                  const int* __restrict__ dst,
                                                  int* __restrict__ cursor,
                                                  int* __restrict__ epacked) {
    __shared__ int hist[NB];
    __shared__ int run[NB];
    int t = threadIdx.x;
    for (int i = t; i < NB; i += 256) hist[i] = 0;
    __syncthreads();

    int base = blockIdx.x * CHUNK;
    int pk[CHUNK / 256];
    int bb[CHUNK / 256];
    #pragma unroll
    for (int i = 0; i < CHUNK / 256; ++i) {
        int e = base + i * 256 + t;
        if (e < GE) {
            int d = dst[e];
            int b = d >> BUCK_SH;
            pk[i] = (src[e] << BUCK_SH) | (d & (BUCKW - 1));
            bb[i] = b;
            atomicAdd(&hist[b], 1);
        } else {
            bb[i] = -1;
        }
    }
    __syncthreads();
    for (int i = t; i < NB; i += 256) {
        int c = hist[i];
        if (c > 0) run[i] = atomicAdd(&cursor[i], c);
    }
    __syncthreads();
    #pragma unroll
    for (int i = 0; i < CHUNK / 256; ++i) {
        if (bb[i] >= 0) {
            int pos = atomicAdd(&run[bb[i]], 1);
            epacked[pos] = pk[i];
        }
    }
}

// ---------------------------------------------------------------------------
// K5: bucket gather. One block per bucket: 128 dsts x 64 feats fp32 accum in
// LDS (stride 65 -> bank = (dl + j) % 32, spread by random dl). Edge-per-
// thread: expf once, ds_add_f32 den + 64 weighted feats. Fused /den + ELU +
// coalesced store. Writes EVERY dst of the bucket -> full out coverage.
// ---------------------------------------------------------------------------
__global__ __launch_bounds__(256) void k_bgather(const int* __restrict__ bbase,
                                                 const int* __restrict__ cursor,
                                                 const int* __restrict__ epacked,
                                                 const float* __restrict__ s1,
                                                 const float* __restrict__ s2,
                                                 const float* __restrict__ Wh,
                                                 float* __restrict__ out) {
    __shared__ float acc[BUCKW * ACC_STRIDE];  // 33.3 KB
    __shared__ float den[BUCKW];
    __shared__ float s2l[BUCKW];
    int t = threadIdx.x;
    int b = blockIdx.x;
    int dstbase = b * BUCKW;
    int nd = GN - dstbase; if (nd > BUCKW) nd = BUCKW;

    for (int i = t; i < BUCKW * ACC_STRIDE; i += 256) acc[i] = 0.f;
    for (int i = t; i < BUCKW; i += 256) {
        den[i] = 0.f;
        s2l[i] = (i < nd) ? s2[dstbase + i] : 0.f;
    }
    __syncthreads();

    int start = bbase[b];
    int end   = cursor[b];
    for (int i = start + t; i < end; i += 256) {
        int pk = epacked[i];
        int s  = pk >> BUCK_SH;
        int dl = pk & (BUCKW - 1);
        float x = s1[s] + s2l[dl];
        x = (x > 0.f) ? x : LRELU_ALPHA * x;
        float ex = expf(x);
        atomicAdd(&den[dl], ex);
        const float4* wp = (const float4*)&Wh[s * OUTF];
        float* ap = &acc[dl * ACC_STRIDE];
        #pragma unroll
        for (int j4 = 0; j4 < OUTF / 4; ++j4) {
            float4 wv = wp[j4];
            atomicAdd(ap + j4 * 4 + 0, ex * wv.x);
            atomicAdd(ap + j4 * 4 + 1, ex * wv.y);
            atomicAdd(ap + j4 * 4 + 2, ex * wv.z);
            atomicAdd(ap + j4 * 4 + 3, ex * wv.w);
        }
    }
    __syncthreads();

    for (int idx = t; idx < nd * OUTF; idx += 256) {
        int dl = idx >> 6;
        int j  = idx & (OUTF - 1);
        float d = den[dl];
        float inv = (d > 0.f) ? 1.f / d : 0.f;
        float o = acc[dl * ACC_STRIDE + j] * inv;
        o = (o > 0.f) ? o : expm1f(o);
        out[(dstbase + dl) * OUTF + j] = o;
    }
}

extern "C" void kernel_launch(void* const* d_in, const int* in_sizes, int n_in,
                              void* d_out, int out_size, void* d_ws, size_t ws_size,
                              hipStream_t stream) {
    const float* h  = (const float*)d_in[0];
    const int*   ei = (const int*)d_in[1];    // [2, E]: first E = src, next E = dst
    const float* W  = (const float*)d_in[2];
    const float* a  = (const float*)d_in[3];
    const int* src = ei;
    const int* dst = ei + GE;

    float* ws = (float*)d_ws;
    float* s1 = ws;                                   // N
    float* s2 = s1 + GN;                              // N
    float* Wh = s2 + GN;                              // N*64
    int* epacked = (int*)(Wh + (size_t)GN * OUTF);    // E
    int* bcnt    = epacked + GE;                      // NB
    int* bbase   = bcnt + NB;                         // NB
    int* cursor  = bbase + NB;                        // NB
    float* out = (float*)d_out;

    k_zero<<<(NB + 255) / 256, 256, 0, stream>>>(bcnt);
    k_gemm<<<(GN + 15) / 16, 256, 0, stream>>>(h, W, a, Wh, s1, s2);
    k_chist<<<NCH, 256, 0, stream>>>(dst, bcnt);
    k_scan<<<1, 512, 0, stream>>>(bcnt, bbase, cursor);
    k_mscatter<<<NCH, 256, 0, stream>>>(src, dst, cursor, epacked);
    k_bgather<<<NB, 256, 0, stream>>>(bbase, cursor, epacked, s1, s2, Wh, out);
}

// Round 5
// 162.799 us; speedup vs baseline: 2.9676x; 2.9676x over previous
//
#include <hip/hip_runtime.h>
#include <math.h>

#define GN 50000
#define GE 800000
#define INF 128
#define OUTF 64
#define LRELU_ALPHA 0.2f

#define BUCK_SH 6                          // bucket = dst >> 6  (64 dsts/bucket)
#define BUCKW   64
#define NB      ((GN + BUCKW - 1) / BUCKW) // 782 buckets
#define CHUNK   4096                       // edges per chist/mscatter block
#define NCH     ((GE + CHUNK - 1) / CHUNK) // 196 chunks
#define CAP     1536                       // bucket edge capacity (mean 1024, +16 sigma)

// ---------------------------------------------------------------------------
// K0: zero the per-bucket edge counts (tiny).
// ---------------------------------------------------------------------------
__global__ __launch_bounds__(256) void k_zero(int* __restrict__ bcnt) {
    int i = blockIdx.x * 256 + threadIdx.x;
    if (i < NB) bcnt[i] = 0;
}

// ---------------------------------------------------------------------------
// K1: Wh = h @ W (N x 128 @ 128 x 64), fused s1 = Wh@a1, s2 = Wh@a2.
// (unchanged; ~33us LDS-read-bound, next round's target)
// ---------------------------------------------------------------------------
__global__ __launch_bounds__(256) void k_gemm(const float* __restrict__ h,
                                              const float* __restrict__ W,
                                              const float* __restrict__ a,
                                              float* __restrict__ Wh,
                                              float* __restrict__ s1,
                                              float* __restrict__ s2) {
    __shared__ __align__(16) float Wlds[INF * OUTF];  // 32 KB
    int t = threadIdx.x;
    for (int i = t * 4; i < INF * OUTF; i += 256 * 4) {
        *(float4*)&Wlds[i] = *(const float4*)&W[i];
    }
    __syncthreads();

    int node = blockIdx.x * 16 + (t >> 4);
    int jg   = (t & 15) * 4;
    if (node >= GN) return;

    const float4* h4 = (const float4*)&h[node * INF];
    float4 acc = {0.f, 0.f, 0.f, 0.f};
    #pragma unroll
    for (int k4 = 0; k4 < INF / 4; ++k4) {
        float4 hv = h4[k4];
        int k = k4 * 4;
        float4 w0 = *(float4*)&Wlds[(k + 0) * OUTF + jg];
        float4 w1 = *(float4*)&Wlds[(k + 1) * OUTF + jg];
        float4 w2 = *(float4*)&Wlds[(k + 2) * OUTF + jg];
        float4 w3 = *(float4*)&Wlds[(k + 3) * OUTF + jg];
        acc.x += hv.x * w0.x + hv.y * w1.x + hv.z * w2.x + hv.w * w3.x;
        acc.y += hv.x * w0.y + hv.y * w1.y + hv.z * w2.y + hv.w * w3.y;
        acc.z += hv.x * w0.z + hv.y * w1.z + hv.z * w2.z + hv.w * w3.z;
        acc.w += hv.x * w0.w + hv.y * w1.w + hv.z * w2.w + hv.w * w3.w;
    }
    *(float4*)&Wh[node * OUTF + jg] = acc;

    float p1 = acc.x * a[jg]        + acc.y * a[jg + 1]
             + acc.z * a[jg + 2]    + acc.w * a[jg + 3];
    float p2 = acc.x * a[OUTF + jg]     + acc.y * a[OUTF + jg + 1]
             + acc.z * a[OUTF + jg + 2] + acc.w * a[OUTF + jg + 3];
    #pragma unroll
    for (int off = 8; off >= 1; off >>= 1) {
        p1 += __shfl_down(p1, off, 16);
        p2 += __shfl_down(p2, off, 16);
    }
    if ((t & 15) == 0) {
        s1[node] = p1;
        s2[node] = p2;
    }
}

// ---------------------------------------------------------------------------
// K2: coarse histogram: per-block LDS hist of dst>>6 -> global bucket counts.
// ---------------------------------------------------------------------------
__global__ __launch_bounds__(256) void k_chist(const int* __restrict__ dst,
                                               int* __restrict__ bcnt) {
    __shared__ int hist[NB];
    int t = threadIdx.x;
    for (int i = t; i < NB; i += 256) hist[i] = 0;
    __syncthreads();
    int base = blockIdx.x * CHUNK;
    #pragma unroll
    for (int i = 0; i < CHUNK / 256; ++i) {
        int e = base + i * 256 + t;
        if (e < GE) atomicAdd(&hist[dst[e] >> BUCK_SH], 1);
    }
    __syncthreads();
    for (int i = t; i < NB; i += 256) {
        int c = hist[i];
        if (c > 0) atomicAdd(&bcnt[i], c);
    }
}

// ---------------------------------------------------------------------------
// K3: single block (1024 thr): exclusive scan of NB bucket counts.
// ---------------------------------------------------------------------------
__global__ __launch_bounds__(1024) void k_scan(const int* __restrict__ bcnt,
                                               int* __restrict__ bbase,
                                               int* __restrict__ cursor) {
    __shared__ int lds[1024];
    int t = threadIdx.x;
    int v = (t < NB) ? bcnt[t] : 0;
    lds[t] = v;
    __syncthreads();
    #pragma unroll
    for (int off = 1; off < 1024; off <<= 1) {
        int u = (t >= off) ? lds[t - off] : 0;
        __syncthreads();
        lds[t] += u;
        __syncthreads();
    }
    if (t < NB) {
        int b = lds[t] - v;   // exclusive
        bbase[t]  = b;
        cursor[t] = b;
    }
}

// ---------------------------------------------------------------------------
// K4: multisplit scatter. Each block reserves one contiguous run per bucket
// (global atomic on cursor), fills via LDS cursors. Afterwards cursor[b] ==
// end of bucket b. Payload: (src << 6) | (dst & 63).
// ---------------------------------------------------------------------------
__global__ __launch_bounds__(256) void k_mscatter(const int* __restrict__ src,
                                                  const int* __restrict__ dst,
                                                  int* __restrict__ cursor,
                                                  int* __restrict__ epacked) {
    __shared__ int hist[NB];
    __shared__ int run[NB];
    int t = threadIdx.x;
    for (int i = t; i < NB; i += 256) hist[i] = 0;
    __syncthreads();

    int base = blockIdx.x * CHUNK;
    int pk[CHUNK / 256];
    int bb[CHUNK / 256];
    #pragma unroll
    for (int i = 0; i < CHUNK / 256; ++i) {
        int e = base + i * 256 + t;
        if (e < GE) {
            int d = dst[e];
            int b = d >> BUCK_SH;
            pk[i] = (src[e] << BUCK_SH) | (d & (BUCKW - 1));
            bb[i] = b;
            atomicAdd(&hist[b], 1);
        } else {
            bb[i] = -1;
        }
    }
    __syncthreads();
    for (int i = t; i < NB; i += 256) {
        int c = hist[i];
        if (c > 0) run[i] = atomicAdd(&cursor[i], c);
    }
    __syncthreads();
    #pragma unroll
    for (int i = 0; i < CHUNK / 256; ++i) {
        if (bb[i] >= 0) {
            int pos = atomicAdd(&run[bb[i]], 1);
            epacked[pos] = pk[i];
        }
    }
}

// ---------------------------------------------------------------------------
// K5: fused sort + softmax + aggregation + ELU. 2 blocks per bucket (feature
// halves). Load bucket edges to LDS, 64-bin counting sort (1 LDS atomic per
// edge), then 8-lane groups per dst: shfl-broadcast expf, COALESCED 128B Wh
// reads, register accumulators, fused /den + ELU + coalesced store.
// ---------------------------------------------------------------------------
__global__ __launch_bounds__(256) void k_fgather(const int* __restrict__ bbase,
                                                 const int* __restrict__ bend,
                                                 const int* __restrict__ epacked,
                                                 const float* __restrict__ s1,
                                                 const float* __restrict__ s2,
                                                 const float* __restrict__ Wh,
                                                 float* __restrict__ out) {
    __shared__ int elds[CAP];
    __shared__ int sorted[CAP];
    __shared__ int hist[BUCKW];
    __shared__ int cur[BUCKW];
    __shared__ int cstart[BUCKW + 1];
    __shared__ float s2l[BUCKW];

    int t  = threadIdx.x;
    int b  = blockIdx.x >> 1;
    int fh = blockIdx.x & 1;            // feature half: 0 -> feats 0..31, 1 -> 32..63
    int dstbase = b * BUCKW;
    int nd = GN - dstbase; if (nd > BUCKW) nd = BUCKW;

    int start = bbase[b];
    int cnt   = bend[b] - start;
    if (cnt > CAP) cnt = CAP;           // statistically impossible; safety only

    if (t < BUCKW) {
        hist[t] = 0;
        s2l[t] = (t < nd) ? s2[dstbase + t] : 0.f;
    }
    __syncthreads();
    for (int i = t; i < cnt; i += 256) {
        int pk = epacked[start + i];
        elds[i] = pk;
        atomicAdd(&hist[pk & (BUCKW - 1)], 1);
    }
    __syncthreads();
    if (t < 64) {                        // wave 0: inclusive scan of 64 bins
        int v = hist[t];
        int incl = v;
        #pragma unroll
        for (int off = 1; off < 64; off <<= 1) {
            int u = __shfl_up(incl, off, 64);
            if (t >= off) incl += u;
        }
        cstart[t + 1] = incl;
        cur[t] = incl - v;
        if (t == 0) cstart[0] = 0;
    }
    __syncthreads();
    for (int i = t; i < cnt; i += 256) {
        int pk = elds[i];
        int pos = atomicAdd(&cur[pk & (BUCKW - 1)], 1);
        sorted[pos] = pk;
    }
    __syncthreads();

    int grp  = t >> 3;                   // 32 groups of 8 lanes
    int lane = t & 7;
    int jg   = fh * 32 + lane * 4;
    for (int dl = grp; dl < BUCKW; dl += 32) {
        int c0 = cstart[dl], c1 = cstart[dl + 1];
        float4 acc = {0.f, 0.f, 0.f, 0.f};
        float den = 0.f;
        float s2n = s2l[dl];
        for (int cb = c0; cb < c1; cb += 8) {
            int my = cb + lane;
            float ex_l = 0.f; int s_l = 0;
            if (my < c1) {
                int pk = sorted[my];
                s_l = pk >> BUCK_SH;
                float x = s1[s_l] + s2n;
                x = (x > 0.f) ? x : LRELU_ALPHA * x;
                ex_l = expf(x);
            }
            int m = c1 - cb; if (m > 8) m = 8;
            for (int j = 0; j < m; ++j) {
                float ex = __shfl(ex_l, j, 8);
                int   s  = __shfl(s_l,  j, 8);
                den += ex;
                float4 wv = *(const float4*)&Wh[s * OUTF + jg];
                acc.x += ex * wv.x;
                acc.y += ex * wv.y;
                acc.z += ex * wv.z;
                acc.w += ex * wv.w;
            }
        }
        if (dl < nd) {
            float inv = (c1 > c0) ? 1.f / den : 0.f;
            float4 o;
            o.x = acc.x * inv; o.y = acc.y * inv;
            o.z = acc.z * inv; o.w = acc.w * inv;
            o.x = (o.x > 0.f) ? o.x : expm1f(o.x);
            o.y = (o.y > 0.f) ? o.y : expm1f(o.y);
            o.z = (o.z > 0.f) ? o.z : expm1f(o.z);
            o.w = (o.w > 0.f) ? o.w : expm1f(o.w);
            *(float4*)&out[(dstbase + dl) * OUTF + jg] = o;
        }
    }
}

extern "C" void kernel_launch(void* const* d_in, const int* in_sizes, int n_in,
                              void* d_out, int out_size, void* d_ws, size_t ws_size,
                              hipStream_t stream) {
    const float* h  = (const float*)d_in[0];
    const int*   ei = (const int*)d_in[1];    // [2, E]: first E = src, next E = dst
    const float* W  = (const float*)d_in[2];
    const float* a  = (const float*)d_in[3];
    const int* src = ei;
    const int* dst = ei + GE;

    float* ws = (float*)d_ws;
    float* s1 = ws;                                   // N
    float* s2 = s1 + GN;                              // N
    float* Wh = s2 + GN;                              // N*64
    int* epacked = (int*)(Wh + (size_t)GN * OUTF);    // E
    int* bcnt    = epacked + GE;                      // NB
    int* bbase   = bcnt + NB;                         // NB
    int* cursor  = bbase + NB;                        // NB
    float* out = (float*)d_out;

    k_zero<<<(NB + 255) / 256, 256, 0, stream>>>(bcnt);
    k_gemm<<<(GN + 15) / 16, 256, 0, stream>>>(h, W, a, Wh, s1, s2);
    k_chist<<<NCH, 256, 0, stream>>>(dst, bcnt);
    k_scan<<<1, 1024, 0, stream>>>(bcnt, bbase, cursor);
    k_mscatter<<<NCH, 256, 0, stream>>>(src, dst, cursor, epacked);
    k_fgather<<<NB * 2, 256, 0, stream>>>(bbase, cursor, epacked, s1, s2, Wh, out);
}

// Round 6
// 156.934 us; speedup vs baseline: 3.0786x; 1.0374x over previous
//
#include <hip/hip_runtime.h>
#include <math.h>

#define GN 50000
#define GE 800000
#define INF 128
#define OUTF 64
#define LRELU_ALPHA 0.2f

#define BUCK_SH 6                          // bucket = dst >> 6  (64 dsts/bucket)
#define BUCKW   64
#define NB      ((GN + BUCKW - 1) / BUCKW) // 782 buckets
#define CHUNK   4096                       // edges per chist/mscatter block
#define NCH     ((GE + CHUNK - 1) / CHUNK) // 196 chunks
#define CAP     1536                       // bucket capacity (mean 1024, +16 sigma)

// ---- bf16 helpers (RNE pack, cheap unpack) --------------------------------
__device__ __forceinline__ unsigned short f32_to_bf16(float f) {
    unsigned int u = __float_as_uint(f);
    return (unsigned short)((u + 0x7fffu + ((u >> 16) & 1u)) >> 16);
}
__device__ __forceinline__ float bf16lo(unsigned int u) { return __uint_as_float(u << 16); }
__device__ __forceinline__ float bf16hi(unsigned int u) { return __uint_as_float(u & 0xffff0000u); }

// ---------------------------------------------------------------------------
// K0: zero the per-bucket edge counts (tiny).
// ---------------------------------------------------------------------------
__global__ __launch_bounds__(256) void k_zero(int* __restrict__ bcnt) {
    int i = blockIdx.x * 256 + threadIdx.x;
    if (i < NB) bcnt[i] = 0;
}

// ---------------------------------------------------------------------------
// K1: Wh = h @ W, register-blocked 4 nodes/thread: one W float4 LDS read
// feeds 16 FMAs (4x less LDS traffic than R5). h read from global with
// 16-lane broadcast (L1-served). Outputs: Whb (bf16, for the gather) and
// fp32 s1/s2 (from the fp32 accumulators -> exp path keeps full precision).
// 64 nodes/block, 782 blocks.
// ---------------------------------------------------------------------------
__global__ __launch_bounds__(256) void k_gemm(const float* __restrict__ h,
                                              const float* __restrict__ W,
                                              const float* __restrict__ a,
                                              unsigned short* __restrict__ Whb,
                                              float* __restrict__ s1,
                                              float* __restrict__ s2) {
    __shared__ __align__(16) float Wlds[INF * OUTF];  // 32 KB
    int t = threadIdx.x;
    for (int i = t * 4; i < INF * OUTF; i += 256 * 4)
        *(float4*)&Wlds[i] = *(const float4*)&W[i];
    __syncthreads();

    int fg = t & 15;           // feature group: 4 feats
    int ng = t >> 4;           // node group: 4 nodes
    int jg = fg * 4;
    int n0 = blockIdx.x * 64 + ng * 4;

    int m0 = n0 + 0 < GN ? n0 + 0 : GN - 1;   // clamp loads; stores guarded
    int m1 = n0 + 1 < GN ? n0 + 1 : GN - 1;
    int m2 = n0 + 2 < GN ? n0 + 2 : GN - 1;
    int m3 = n0 + 3 < GN ? n0 + 3 : GN - 1;
    const float* h0 = &h[m0 * INF];
    const float* h1 = &h[m1 * INF];
    const float* h2 = &h[m2 * INF];
    const float* h3 = &h[m3 * INF];

    float4 acc0 = {0.f,0.f,0.f,0.f}, acc1 = acc0, acc2 = acc0, acc3 = acc0;
    for (int kc = 0; kc < INF; kc += 4) {
        float4 hv0 = *(const float4*)&h0[kc];
        float4 hv1 = *(const float4*)&h1[kc];
        float4 hv2 = *(const float4*)&h2[kc];
        float4 hv3 = *(const float4*)&h3[kc];
        #pragma unroll
        for (int kk = 0; kk < 4; ++kk) {
            float4 wv = *(float4*)&Wlds[(kc + kk) * OUTF + jg];
            float a0 = ((const float*)&hv0)[kk];
            float a1v = ((const float*)&hv1)[kk];
            float a2v = ((const float*)&hv2)[kk];
            float a3 = ((const float*)&hv3)[kk];
            acc0.x += a0 * wv.x; acc0.y += a0 * wv.y; acc0.z += a0 * wv.z; acc0.w += a0 * wv.w;
            acc1.x += a1v * wv.x; acc1.y += a1v * wv.y; acc1.z += a1v * wv.z; acc1.w += a1v * wv.w;
            acc2.x += a2v * wv.x; acc2.y += a2v * wv.y; acc2.z += a2v * wv.z; acc2.w += a2v * wv.w;
            acc3.x += a3 * wv.x; acc3.y += a3 * wv.y; acc3.z += a3 * wv.z; acc3.w += a3 * wv.w;
        }
    }

    // bf16 pack + store (8B per node-row slice, coalesced across fg)
    float4 accs[4] = {acc0, acc1, acc2, acc3};
    #pragma unroll
    for (int i = 0; i < 4; ++i) {
        if (n0 + i < GN) {
            ushort4 p;
            p.x = f32_to_bf16(accs[i].x); p.y = f32_to_bf16(accs[i].y);
            p.z = f32_to_bf16(accs[i].z); p.w = f32_to_bf16(accs[i].w);
            *(ushort4*)&Whb[(n0 + i) * OUTF + jg] = p;
        }
    }

    // s1/s2 from fp32 accumulators
    float4 va1 = *(const float4*)&a[jg];
    float4 va2 = *(const float4*)&a[OUTF + jg];
    float p1[4], p2[4];
    #pragma unroll
    for (int i = 0; i < 4; ++i) {
        p1[i] = accs[i].x * va1.x + accs[i].y * va1.y + accs[i].z * va1.z + accs[i].w * va1.w;
        p2[i] = accs[i].x * va2.x + accs[i].y * va2.y + accs[i].z * va2.z + accs[i].w * va2.w;
    }
    #pragma unroll
    for (int off = 8; off >= 1; off >>= 1) {
        #pragma unroll
        for (int i = 0; i < 4; ++i) {
            p1[i] += __shfl_down(p1[i], off, 16);
            p2[i] += __shfl_down(p2[i], off, 16);
        }
    }
    if (fg == 0) {
        #pragma unroll
        for (int i = 0; i < 4; ++i) {
            if (n0 + i < GN) { s1[n0 + i] = p1[i]; s2[n0 + i] = p2[i]; }
        }
    }
}

// ---------------------------------------------------------------------------
// K2: coarse histogram: per-block LDS hist of dst>>6 -> global bucket counts.
// ---------------------------------------------------------------------------
__global__ __launch_bounds__(256) void k_chist(const int* __restrict__ dst,
                                               int* __restrict__ bcnt) {
    __shared__ int hist[NB];
    int t = threadIdx.x;
    for (int i = t; i < NB; i += 256) hist[i] = 0;
    __syncthreads();
    int base = blockIdx.x * CHUNK;
    #pragma unroll
    for (int i = 0; i < CHUNK / 256; ++i) {
        int e = base + i * 256 + t;
        if (e < GE) atomicAdd(&hist[dst[e] >> BUCK_SH], 1);
    }
    __syncthreads();
    for (int i = t; i < NB; i += 256) {
        int c = hist[i];
        if (c > 0) atomicAdd(&bcnt[i], c);
    }
}

// ---------------------------------------------------------------------------
// K3: single block (1024 thr): exclusive scan of NB bucket counts.
// ---------------------------------------------------------------------------
__global__ __launch_bounds__(1024) void k_scan(const int* __restrict__ bcnt,
                                               int* __restrict__ bbase,
                                               int* __restrict__ cursor) {
    __shared__ int lds[1024];
    int t = threadIdx.x;
    int v = (t < NB) ? bcnt[t] : 0;
    lds[t] = v;
    __syncthreads();
    #pragma unroll
    for (int off = 1; off < 1024; off <<= 1) {
        int u = (t >= off) ? lds[t - off] : 0;
        __syncthreads();
        lds[t] += u;
        __syncthreads();
    }
    if (t < NB) {
        int b = lds[t] - v;   // exclusive
        bbase[t]  = b;
        cursor[t] = b;
    }
}

// ---------------------------------------------------------------------------
// K4: multisplit scatter: one contiguous run per (block,bucket) via a single
// global atomic -> near-full-line writebacks. cursor[b] ends at bucket end.
// Payload: (src << 6) | (dst & 63).
// ---------------------------------------------------------------------------
__global__ __launch_bounds__(256) void k_mscatter(const int* __restrict__ src,
                                                  const int* __restrict__ dst,
                                                  int* __restrict__ cursor,
                                                  int* __restrict__ epacked) {
    __shared__ int hist[NB];
    __shared__ int run[NB];
    int t = threadIdx.x;
    for (int i = t; i < NB; i += 256) hist[i] = 0;
    __syncthreads();

    int base = blockIdx.x * CHUNK;
    int pk[CHUNK / 256];
    int bb[CHUNK / 256];
    #pragma unroll
    for (int i = 0; i < CHUNK / 256; ++i) {
        int e = base + i * 256 + t;
        if (e < GE) {
            int d = dst[e];
            int b = d >> BUCK_SH;
            pk[i] = (src[e] << BUCK_SH) | (d & (BUCKW - 1));
            bb[i] = b;
            atomicAdd(&hist[b], 1);
        } else {
            bb[i] = -1;
        }
    }
    __syncthreads();
    for (int i = t; i < NB; i += 256) {
        int c = hist[i];
        if (c > 0) run[i] = atomicAdd(&cursor[i], c);
    }
    __syncthreads();
    #pragma unroll
    for (int i = 0; i < CHUNK / 256; ++i) {
        if (bb[i] >= 0) {
            int pos = atomicAdd(&run[bb[i]], 1);
            epacked[pos] = pk[i];
        }
    }
}

// ---------------------------------------------------------------------------
// K5: fused sort + softmax + aggregation + ELU. ONE block per bucket (sort
// once). 32 groups x 8 lanes; each lane covers 8 feats of the bf16 Wh row
// (16B uint4 read -> whole 128B row coalesced by the group). Register
// accumulators, shfl-broadcast expf, fused /den + ELU + coalesced store.
// ---------------------------------------------------------------------------
__global__ __launch_bounds__(256) void k_fgather(const int* __restrict__ bbase,
                                                 const int* __restrict__ bend,
                                                 const int* __restrict__ epacked,
                                                 const float* __restrict__ s1,
                                                 const float* __restrict__ s2,
                                                 const unsigned short* __restrict__ Whb,
                                                 float* __restrict__ out) {
    __shared__ int elds[CAP];
    __shared__ int sorted[CAP];
    __shared__ int hist[BUCKW];
    __shared__ int cur[BUCKW];
    __shared__ int cstart[BUCKW + 1];
    __shared__ float s2l[BUCKW];

    int t = threadIdx.x;
    int b = blockIdx.x;
    int dstbase = b * BUCKW;
    int nd = GN - dstbase; if (nd > BUCKW) nd = BUCKW;

    int start = bbase[b];
    int cnt   = bend[b] - start;
    if (cnt > CAP) cnt = CAP;           // statistically impossible; safety only

    if (t < BUCKW) {
        hist[t] = 0;
        s2l[t] = (t < nd) ? s2[dstbase + t] : 0.f;
    }
    __syncthreads();
    for (int i = t; i < cnt; i += 256) {
        int pk = epacked[start + i];
        elds[i] = pk;
        atomicAdd(&hist[pk & (BUCKW - 1)], 1);
    }
    __syncthreads();
    if (t < 64) {                        // wave 0: inclusive scan of 64 bins
        int v = hist[t];
        int incl = v;
        #pragma unroll
        for (int off = 1; off < 64; off <<= 1) {
            int u = __shfl_up(incl, off, 64);
            if (t >= off) incl += u;
        }
        cstart[t + 1] = incl;
        cur[t] = incl - v;
        if (t == 0) cstart[0] = 0;
    }
    __syncthreads();
    for (int i = t; i < cnt; i += 256) {
        int pk = elds[i];
        int pos = atomicAdd(&cur[pk & (BUCKW - 1)], 1);
        sorted[pos] = pk;
    }
    __syncthreads();

    int grp  = t >> 3;                   // 32 groups of 8 lanes
    int lane = t & 7;
    int jg   = lane * 8;                 // 8 feats per lane
    for (int dl = grp; dl < BUCKW; dl += 32) {
        int c0 = cstart[dl], c1 = cstart[dl + 1];
        float acc[8] = {0.f,0.f,0.f,0.f,0.f,0.f,0.f,0.f};
        float den = 0.f;
        float s2n = s2l[dl];
        for (int cb = c0; cb < c1; cb += 8) {
            int my = cb + lane;
            float ex_l = 0.f; int s_l = 0;
            if (my < c1) {
                int pk = sorted[my];
                s_l = pk >> BUCK_SH;
                float x = s1[s_l] + s2n;
                x = (x > 0.f) ? x : LRELU_ALPHA * x;
                ex_l = expf(x);
            }
            int m = c1 - cb; if (m > 8) m = 8;
            for (int j = 0; j < m; ++j) {
                float ex = __shfl(ex_l, j, 8);
                int   s  = __shfl(s_l,  j, 8);
                den += ex;
                uint4 wv = *(const uint4*)&Whb[s * OUTF + jg];
                acc[0] += ex * bf16lo(wv.x); acc[1] += ex * bf16hi(wv.x);
                acc[2] += ex * bf16lo(wv.y); acc[3] += ex * bf16hi(wv.y);
                acc[4] += ex * bf16lo(wv.z); acc[5] += ex * bf16hi(wv.z);
                acc[6] += ex * bf16lo(wv.w); acc[7] += ex * bf16hi(wv.w);
            }
        }
        if (dl < nd) {
            float inv = (c1 > c0) ? 1.f / den : 0.f;
            float o[8];
            #pragma unroll
            for (int j = 0; j < 8; ++j) {
                float v = acc[j] * inv;
                o[j] = (v > 0.f) ? v : expm1f(v);
            }
            float* op = &out[(dstbase + dl) * OUTF + jg];
            *(float4*)(op + 0) = make_float4(o[0], o[1], o[2], o[3]);
            *(float4*)(op + 4) = make_float4(o[4], o[5], o[6], o[7]);
        }
    }
}

extern "C" void kernel_launch(void* const* d_in, const int* in_sizes, int n_in,
                              void* d_out, int out_size, void* d_ws, size_t ws_size,
                              hipStream_t stream) {
    const float* h  = (const float*)d_in[0];
    const int*   ei = (const int*)d_in[1];    // [2, E]: first E = src, next E = dst
    const float* W  = (const float*)d_in[2];
    const float* a  = (const float*)d_in[3];
    const int* src = ei;
    const int* dst = ei + GE;

    float* ws = (float*)d_ws;
    float* s1 = ws;                                          // N
    float* s2 = s1 + GN;                                     // N
    unsigned short* Whb = (unsigned short*)(s2 + GN);        // N*64 bf16
    int* epacked = (int*)(Whb + (size_t)GN * OUTF);          // E
    int* bcnt    = epacked + GE;                             // NB
    int* bbase   = bcnt + NB;                                // NB
    int* cursor  = bbase + NB;                               // NB
    float* out = (float*)d_out;

    k_zero<<<(NB + 255) / 256, 256, 0, stream>>>(bcnt);
    k_gemm<<<(GN + 63) / 64, 256, 0, stream>>>(h, W, a, Whb, s1, s2);
    k_chist<<<NCH, 256, 0, stream>>>(dst, bcnt);
    k_scan<<<1, 1024, 0, stream>>>(bcnt, bbase, cursor);
    k_mscatter<<<NCH, 256, 0, stream>>>(src, dst, cursor, epacked);
    k_fgather<<<NB, 256, 0, stream>>>(bbase, cursor, epacked, s1, s2, Whb, out);
}

// Round 7
// 140.549 us; speedup vs baseline: 3.4374x; 1.1166x over previous
//
#include <hip/hip_runtime.h>
#include <math.h>

#define GN 50000
#define GE 800000
#define INF 128
#define OUTF 64
#define LRELU_ALPHA 0.2f

#define BUCK_SH 6                          // bucket = dst >> 6  (64 dsts/bucket)
#define BUCKW   64
#define NB      ((GN + BUCKW - 1) / BUCKW) // 782 buckets
#define CHUNK   4096                       // edges per mscatter block
#define NCH     ((GE + CHUNK - 1) / CHUNK) // 196 chunks
#define CAP     1536                       // fixed bucket capacity (mean 1023, +16 sigma)

// ---- bf16 helpers (RNE pack, cheap unpack) --------------------------------
__device__ __forceinline__ unsigned short f32_to_bf16(float f) {
    unsigned int u = __float_as_uint(f);
    return (unsigned short)((u + 0x7fffu + ((u >> 16) & 1u)) >> 16);
}
__device__ __forceinline__ float bf16lo(unsigned int u) { return __uint_as_float(u << 16); }
__device__ __forceinline__ float bf16hi(unsigned int u) { return __uint_as_float(u & 0xffff0000u); }

// ---------------------------------------------------------------------------
// K1: Wh = h @ W (bf16 out) + s1/s2 (fp32) + cursor init (grid == NB blocks;
// same-stream ordering makes the init visible to K2). 4 nodes/thread register
// blocking: one W float4 LDS read feeds 16 FMAs.
// ---------------------------------------------------------------------------
__global__ __launch_bounds__(256) void k_gemm(const float* __restrict__ h,
                                              const float* __restrict__ W,
                                              const float* __restrict__ a,
                                              unsigned short* __restrict__ Whb,
                                              float* __restrict__ s1,
                                              float* __restrict__ s2,
                                              int* __restrict__ cursor) {
    __shared__ __align__(16) float Wlds[INF * OUTF];  // 32 KB
    int t = threadIdx.x;
    if (t == 0) cursor[blockIdx.x] = blockIdx.x * CAP;   // grid = NB = 782
    for (int i = t * 4; i < INF * OUTF; i += 256 * 4)
        *(float4*)&Wlds[i] = *(const float4*)&W[i];
    __syncthreads();

    int fg = t & 15;           // feature group: 4 feats
    int ng = t >> 4;           // node group: 4 nodes
    int jg = fg * 4;
    int n0 = blockIdx.x * 64 + ng * 4;

    int m0 = n0 + 0 < GN ? n0 + 0 : GN - 1;   // clamp loads; stores guarded
    int m1 = n0 + 1 < GN ? n0 + 1 : GN - 1;
    int m2 = n0 + 2 < GN ? n0 + 2 : GN - 1;
    int m3 = n0 + 3 < GN ? n0 + 3 : GN - 1;
    const float* h0 = &h[m0 * INF];
    const float* h1 = &h[m1 * INF];
    const float* h2 = &h[m2 * INF];
    const float* h3 = &h[m3 * INF];

    float4 acc0 = {0.f,0.f,0.f,0.f}, acc1 = acc0, acc2 = acc0, acc3 = acc0;
    for (int kc = 0; kc < INF; kc += 4) {
        float4 hv0 = *(const float4*)&h0[kc];
        float4 hv1 = *(const float4*)&h1[kc];
        float4 hv2 = *(const float4*)&h2[kc];
        float4 hv3 = *(const float4*)&h3[kc];
        #pragma unroll
        for (int kk = 0; kk < 4; ++kk) {
            float4 wv = *(float4*)&Wlds[(kc + kk) * OUTF + jg];
            float a0 = ((const float*)&hv0)[kk];
            float a1v = ((const float*)&hv1)[kk];
            float a2v = ((const float*)&hv2)[kk];
            float a3 = ((const float*)&hv3)[kk];
            acc0.x += a0 * wv.x; acc0.y += a0 * wv.y; acc0.z += a0 * wv.z; acc0.w += a0 * wv.w;
            acc1.x += a1v * wv.x; acc1.y += a1v * wv.y; acc1.z += a1v * wv.z; acc1.w += a1v * wv.w;
            acc2.x += a2v * wv.x; acc2.y += a2v * wv.y; acc2.z += a2v * wv.z; acc2.w += a2v * wv.w;
            acc3.x += a3 * wv.x; acc3.y += a3 * wv.y; acc3.z += a3 * wv.z; acc3.w += a3 * wv.w;
        }
    }

    float4 accs[4] = {acc0, acc1, acc2, acc3};
    #pragma unroll
    for (int i = 0; i < 4; ++i) {
        if (n0 + i < GN) {
            ushort4 p;
            p.x = f32_to_bf16(accs[i].x); p.y = f32_to_bf16(accs[i].y);
            p.z = f32_to_bf16(accs[i].z); p.w = f32_to_bf16(accs[i].w);
            *(ushort4*)&Whb[(n0 + i) * OUTF + jg] = p;
        }
    }

    float4 va1 = *(const float4*)&a[jg];
    float4 va2 = *(const float4*)&a[OUTF + jg];
    float p1[4], p2[4];
    #pragma unroll
    for (int i = 0; i < 4; ++i) {
        p1[i] = accs[i].x * va1.x + accs[i].y * va1.y + accs[i].z * va1.z + accs[i].w * va1.w;
        p2[i] = accs[i].x * va2.x + accs[i].y * va2.y + accs[i].z * va2.z + accs[i].w * va2.w;
    }
    #pragma unroll
    for (int off = 8; off >= 1; off >>= 1) {
        #pragma unroll
        for (int i = 0; i < 4; ++i) {
            p1[i] += __shfl_down(p1[i], off, 16);
            p2[i] += __shfl_down(p2[i], off, 16);
        }
    }
    if (fg == 0) {
        #pragma unroll
        for (int i = 0; i < 4; ++i) {
            if (n0 + i < GN) { s1[n0 + i] = p1[i]; s2[n0 + i] = p2[i]; }
        }
    }
}

// ---------------------------------------------------------------------------
// K2: multisplit into fixed-capacity bucket regions. One contiguous run per
// (block,bucket) reserved with a single global atomic on cursor[b] (which
// k_gemm initialized to b*CAP). Payload: (src << 6) | (dst & 63).
// ---------------------------------------------------------------------------
__global__ __launch_bounds__(256) void k_mscatter(const int* __restrict__ src,
                                                  const int* __restrict__ dst,
                                                  int* __restrict__ cursor,
                                                  int* __restrict__ epacked) {
    __shared__ int hist[NB];
    __shared__ int run[NB];
    int t = threadIdx.x;
    for (int i = t; i < NB; i += 256) hist[i] = 0;
    __syncthreads();

    int base = blockIdx.x * CHUNK;
    int pk[CHUNK / 256];
    int bb[CHUNK / 256];
    #pragma unroll
    for (int i = 0; i < CHUNK / 256; ++i) {
        int e = base + i * 256 + t;
        if (e < GE) {
            int d = dst[e];
            int b = d >> BUCK_SH;
            pk[i] = (src[e] << BUCK_SH) | (d & (BUCKW - 1));
            bb[i] = b;
            atomicAdd(&hist[b], 1);
        } else {
            bb[i] = -1;
        }
    }
    __syncthreads();
    for (int i = t; i < NB; i += 256) {
        int c = hist[i];
        if (c > 0) run[i] = atomicAdd(&cursor[i], c);
    }
    __syncthreads();
    #pragma unroll
    for (int i = 0; i < CHUNK / 256; ++i) {
        if (bb[i] >= 0) {
            int pos = atomicAdd(&run[bb[i]], 1);
            epacked[pos] = pk[i];
        }
    }
}

// ---------------------------------------------------------------------------
// K3: fused sort + softmax + aggregation + ELU, one block per bucket.
// LDS counting sort, then 32 groups x 8 lanes (8 feats/lane). The 8-edge
// chunk loop is FULLY UNROLLED with predication so all 8 independent uint4
// gather loads issue back-to-back (8 outstanding) before any consume --
// ~8x less exposed L2 latency than the rolled loop.
// ---------------------------------------------------------------------------
__global__ __launch_bounds__(256) void k_fgather(const int* __restrict__ cursor,
                                                 const int* __restrict__ epacked,
                                                 const float* __restrict__ s1,
                                                 const float* __restrict__ s2,
                                                 const unsigned short* __restrict__ Whb,
                                                 float* __restrict__ out) {
    __shared__ int elds[CAP];
    __shared__ int sorted[CAP];
    __shared__ int hist[BUCKW];
    __shared__ int cur[BUCKW];
    __shared__ int cstart[BUCKW + 1];
    __shared__ float s2l[BUCKW];

    int t = threadIdx.x;
    int b = blockIdx.x;
    int dstbase = b * BUCKW;
    int nd = GN - dstbase; if (nd > BUCKW) nd = BUCKW;

    int start = b * CAP;
    int cnt   = cursor[b] - start;
    if (cnt > CAP) cnt = CAP;           // statistically impossible; safety only

    if (t < BUCKW) {
        hist[t] = 0;
        s2l[t] = (t < nd) ? s2[dstbase + t] : 0.f;
    }
    __syncthreads();
    for (int i = t; i < cnt; i += 256) {
        int pk = epacked[start + i];
        elds[i] = pk;
        atomicAdd(&hist[pk & (BUCKW - 1)], 1);
    }
    __syncthreads();
    if (t < 64) {                        // wave 0: inclusive scan of 64 bins
        int v = hist[t];
        int incl = v;
        #pragma unroll
        for (int off = 1; off < 64; off <<= 1) {
            int u = __shfl_up(incl, off, 64);
            if (t >= off) incl += u;
        }
        cstart[t + 1] = incl;
        cur[t] = incl - v;
        if (t == 0) cstart[0] = 0;
    }
    __syncthreads();
    for (int i = t; i < cnt; i += 256) {
        int pk = elds[i];
        int pos = atomicAdd(&cur[pk & (BUCKW - 1)], 1);
        sorted[pos] = pk;
    }
    __syncthreads();

    int grp  = t >> 3;                   // 32 groups of 8 lanes
    int lane = t & 7;
    int jg   = lane * 8;                 // 8 feats per lane
    for (int dl = grp; dl < BUCKW; dl += 32) {
        int c0 = cstart[dl], c1 = cstart[dl + 1];
        float acc[8] = {0.f,0.f,0.f,0.f,0.f,0.f,0.f,0.f};
        float den = 0.f;
        float s2n = s2l[dl];
        for (int cb = c0; cb < c1; cb += 8) {
            int my = cb + lane;
            float ex_l = 0.f; int s_l = 0;
            if (my < c1) {
                int pk = sorted[my];
                s_l = pk >> BUCK_SH;
                float x = s1[s_l] + s2n;
                x = (x > 0.f) ? x : LRELU_ALPHA * x;
                ex_l = expf(x);
            }
            int m = c1 - cb; if (m > 8) m = 8;
            int   sj[8]; float exj[8];
            #pragma unroll
            for (int j = 0; j < 8; ++j) {
                exj[j] = __shfl(ex_l, j, 8);
                sj[j]  = __shfl(s_l,  j, 8);
            }
            uint4 wv[8];
            #pragma unroll
            for (int j = 0; j < 8; ++j)
                if (j < m) wv[j] = *(const uint4*)&Whb[sj[j] * OUTF + jg];
            #pragma unroll
            for (int j = 0; j < 8; ++j) {
                if (j < m) {
                    float ex = exj[j];
                    den += ex;
                    acc[0] += ex * bf16lo(wv[j].x); acc[1] += ex * bf16hi(wv[j].x);
                    acc[2] += ex * bf16lo(wv[j].y); acc[3] += ex * bf16hi(wv[j].y);
                    acc[4] += ex * bf16lo(wv[j].z); acc[5] += ex * bf16hi(wv[j].z);
                    acc[6] += ex * bf16lo(wv[j].w); acc[7] += ex * bf16hi(wv[j].w);
                }
            }
        }
        if (dl < nd) {
            float inv = (c1 > c0) ? 1.f / den : 0.f;
            float o[8];
            #pragma unroll
            for (int j = 0; j < 8; ++j) {
                float v = acc[j] * inv;
                o[j] = (v > 0.f) ? v : expm1f(v);
            }
            float* op = &out[(dstbase + dl) * OUTF + jg];
            *(float4*)(op + 0) = make_float4(o[0], o[1], o[2], o[3]);
            *(float4*)(op + 4) = make_float4(o[4], o[5], o[6], o[7]);
        }
    }
}

extern "C" void kernel_launch(void* const* d_in, const int* in_sizes, int n_in,
                              void* d_out, int out_size, void* d_ws, size_t ws_size,
                              hipStream_t stream) {
    const float* h  = (const float*)d_in[0];
    const int*   ei = (const int*)d_in[1];    // [2, E]: first E = src, next E = dst
    const float* W  = (const float*)d_in[2];
    const float* a  = (const float*)d_in[3];
    const int* src = ei;
    const int* dst = ei + GE;

    float* ws = (float*)d_ws;
    float* s1 = ws;                                          // N
    float* s2 = s1 + GN;                                     // N
    unsigned short* Whb = (unsigned short*)(s2 + GN);        // N*64 bf16
    int* epacked = (int*)(Whb + (size_t)GN * OUTF);          // NB*CAP
    int* cursor  = epacked + (size_t)NB * CAP;               // NB
    float* out = (float*)d_out;

    k_gemm<<<NB, 256, 0, stream>>>(h, W, a, Whb, s1, s2, cursor);
    k_mscatter<<<NCH, 256, 0, stream>>>(src, dst, cursor, epacked);
    k_fgather<<<NB, 256, 0, stream>>>(cursor, epacked, s1, s2, Whb, out);
}

// Round 8
// 131.088 us; speedup vs baseline: 3.6855x; 1.0722x over previous
//
#include <hip/hip_runtime.h>
#include <math.h>

#define GN 50000
#define GE 800000
#define INF 128
#define OUTF 64
#define LRELU_ALPHA 0.2f

#define BUCK_SH 6                          // bucket = dst >> 6  (64 dsts/bucket)
#define BUCKW   64
#define NB      ((GN + BUCKW - 1) / BUCKW) // 782 buckets
#define CHUNK   4096                       // edges per mscatter block
#define NCH     ((GE + CHUNK - 1) / CHUNK) // 196 chunks
#define CAP     1536                       // fixed bucket capacity (mean 1023, +16 sigma)

// ---- bf16 helpers (RNE pack, cheap unpack) --------------------------------
__device__ __forceinline__ unsigned short f32_to_bf16(float f) {
    unsigned int u = __float_as_uint(f);
    return (unsigned short)((u + 0x7fffu + ((u >> 16) & 1u)) >> 16);
}
__device__ __forceinline__ float bf16lo(unsigned int u) { return __uint_as_float(u << 16); }
__device__ __forceinline__ float bf16hi(unsigned int u) { return __uint_as_float(u & 0xffff0000u); }

// ---------------------------------------------------------------------------
// K1 "front": blocks [0,NB) run the GEMM (Wh=h@W -> bf16, s1/s2 fp32);
// blocks [NB, NB+NCH) run the edge multisplit. The two halves are data-
// independent, so they overlap: mscatter's latency-bound waves hide under
// gemm's VALU/LDS-bound waves on the same CUs. ccount (per-bucket edge
// count) is zeroed by hipMemsetAsync before launch; epacked positions are
// b*CAP + intra-bucket offset.
// ---------------------------------------------------------------------------
__global__ __launch_bounds__(256) void k_front(const float* __restrict__ h,
                                               const float* __restrict__ W,
                                               const float* __restrict__ a,
                                               const int* __restrict__ src,
                                               const int* __restrict__ dst,
                                               unsigned short* __restrict__ Whb,
                                               float* __restrict__ s1,
                                               float* __restrict__ s2,
                                               int* __restrict__ ccount,
                                               int* __restrict__ epacked) {
    __shared__ __align__(16) float Wlds[INF * OUTF];  // 32 KB (unioned below)
    int t = threadIdx.x;

    if (blockIdx.x < NB) {
        // ================= GEMM half =================
        for (int i = t * 4; i < INF * OUTF; i += 256 * 4)
            *(float4*)&Wlds[i] = *(const float4*)&W[i];
        __syncthreads();

        int fg = t & 15;           // feature group: 4 feats
        int ng = t >> 4;           // node group: 4 nodes
        int jg = fg * 4;
        int n0 = blockIdx.x * 64 + ng * 4;

        int m0 = n0 + 0 < GN ? n0 + 0 : GN - 1;   // clamp loads; stores guarded
        int m1 = n0 + 1 < GN ? n0 + 1 : GN - 1;
        int m2 = n0 + 2 < GN ? n0 + 2 : GN - 1;
        int m3 = n0 + 3 < GN ? n0 + 3 : GN - 1;
        const float* h0 = &h[m0 * INF];
        const float* h1 = &h[m1 * INF];
        const float* h2 = &h[m2 * INF];
        const float* h3 = &h[m3 * INF];

        float4 acc0 = {0.f,0.f,0.f,0.f}, acc1 = acc0, acc2 = acc0, acc3 = acc0;
        for (int kc = 0; kc < INF; kc += 4) {
            float4 hv0 = *(const float4*)&h0[kc];
            float4 hv1 = *(const float4*)&h1[kc];
            float4 hv2 = *(const float4*)&h2[kc];
            float4 hv3 = *(const float4*)&h3[kc];
            #pragma unroll
            for (int kk = 0; kk < 4; ++kk) {
                float4 wv = *(float4*)&Wlds[(kc + kk) * OUTF + jg];
                float a0 = ((const float*)&hv0)[kk];
                float a1v = ((const float*)&hv1)[kk];
                float a2v = ((const float*)&hv2)[kk];
                float a3 = ((const float*)&hv3)[kk];
                acc0.x += a0 * wv.x; acc0.y += a0 * wv.y; acc0.z += a0 * wv.z; acc0.w += a0 * wv.w;
                acc1.x += a1v * wv.x; acc1.y += a1v * wv.y; acc1.z += a1v * wv.z; acc1.w += a1v * wv.w;
                acc2.x += a2v * wv.x; acc2.y += a2v * wv.y; acc2.z += a2v * wv.z; acc2.w += a2v * wv.w;
                acc3.x += a3 * wv.x; acc3.y += a3 * wv.y; acc3.z += a3 * wv.z; acc3.w += a3 * wv.w;
            }
        }

        float4 accs[4] = {acc0, acc1, acc2, acc3};
        #pragma unroll
        for (int i = 0; i < 4; ++i) {
            if (n0 + i < GN) {
                ushort4 p;
                p.x = f32_to_bf16(accs[i].x); p.y = f32_to_bf16(accs[i].y);
                p.z = f32_to_bf16(accs[i].z); p.w = f32_to_bf16(accs[i].w);
                *(ushort4*)&Whb[(n0 + i) * OUTF + jg] = p;
            }
        }

        float4 va1 = *(const float4*)&a[jg];
        float4 va2 = *(const float4*)&a[OUTF + jg];
        float p1[4], p2[4];
        #pragma unroll
        for (int i = 0; i < 4; ++i) {
            p1[i] = accs[i].x * va1.x + accs[i].y * va1.y + accs[i].z * va1.z + accs[i].w * va1.w;
            p2[i] = accs[i].x * va2.x + accs[i].y * va2.y + accs[i].z * va2.z + accs[i].w * va2.w;
        }
        #pragma unroll
        for (int off = 8; off >= 1; off >>= 1) {
            #pragma unroll
            for (int i = 0; i < 4; ++i) {
                p1[i] += __shfl_down(p1[i], off, 16);
                p2[i] += __shfl_down(p2[i], off, 16);
            }
        }
        if (fg == 0) {
            #pragma unroll
            for (int i = 0; i < 4; ++i) {
                if (n0 + i < GN) { s1[n0 + i] = p1[i]; s2[n0 + i] = p2[i]; }
            }
        }
    } else {
        // ================= multisplit half =================
        int* hist = (int*)Wlds;          // NB ints
        int* run  = hist + NB;           // NB ints (6.3 KB total, fits in union)
        for (int i = t; i < NB; i += 256) hist[i] = 0;
        __syncthreads();

        int base = (blockIdx.x - NB) * CHUNK;
        int pk[CHUNK / 256];
        int bb[CHUNK / 256];
        #pragma unroll
        for (int i = 0; i < CHUNK / 256; ++i) {
            int e = base + i * 256 + t;
            if (e < GE) {
                int d = dst[e];
                int b = d >> BUCK_SH;
                pk[i] = (src[e] << BUCK_SH) | (d & (BUCKW - 1));
                bb[i] = b;
                atomicAdd(&hist[b], 1);
            } else {
                bb[i] = -1;
            }
        }
        __syncthreads();
        for (int i = t; i < NB; i += 256) {
            int c = hist[i];
            if (c > 0) run[i] = i * CAP + atomicAdd(&ccount[i], c);
        }
        __syncthreads();
        #pragma unroll
        for (int i = 0; i < CHUNK / 256; ++i) {
            if (bb[i] >= 0) {
                int pos = atomicAdd(&run[bb[i]], 1);
                epacked[pos] = pk[i];
            }
        }
    }
}

// ---------------------------------------------------------------------------
// K2: fused sort + softmax + aggregation + ELU, one block per bucket.
// LDS counting sort, then 32 groups x 8 lanes (8 feats/lane), 8-edge chunks
// fully unrolled with predication (8 outstanding gather loads).
// ---------------------------------------------------------------------------
__global__ __launch_bounds__(256) void k_fgather(const int* __restrict__ ccount,
                                                 const int* __restrict__ epacked,
                                                 const float* __restrict__ s1,
                                                 const float* __restrict__ s2,
                                                 const unsigned short* __restrict__ Whb,
                                                 float* __restrict__ out) {
    __shared__ int elds[CAP];
    __shared__ int sorted[CAP];
    __shared__ int hist[BUCKW];
    __shared__ int cur[BUCKW];
    __shared__ int cstart[BUCKW + 1];
    __shared__ float s2l[BUCKW];

    int t = threadIdx.x;
    int b = blockIdx.x;
    int dstbase = b * BUCKW;
    int nd = GN - dstbase; if (nd > BUCKW) nd = BUCKW;

    int start = b * CAP;
    int cnt   = ccount[b];
    if (cnt > CAP) cnt = CAP;           // statistically impossible; safety only

    if (t < BUCKW) {
        hist[t] = 0;
        s2l[t] = (t < nd) ? s2[dstbase + t] : 0.f;
    }
    __syncthreads();
    for (int i = t; i < cnt; i += 256) {
        int pk = epacked[start + i];
        elds[i] = pk;
        atomicAdd(&hist[pk & (BUCKW - 1)], 1);
    }
    __syncthreads();
    if (t < 64) {                        // wave 0: inclusive scan of 64 bins
        int v = hist[t];
        int incl = v;
        #pragma unroll
        for (int off = 1; off < 64; off <<= 1) {
            int u = __shfl_up(incl, off, 64);
            if (t >= off) incl += u;
        }
        cstart[t + 1] = incl;
        cur[t] = incl - v;
        if (t == 0) cstart[0] = 0;
    }
    __syncthreads();
    for (int i = t; i < cnt; i += 256) {
        int pk = elds[i];
        int pos = atomicAdd(&cur[pk & (BUCKW - 1)], 1);
        sorted[pos] = pk;
    }
    __syncthreads();

    int grp  = t >> 3;                   // 32 groups of 8 lanes
    int lane = t & 7;
    int jg   = lane * 8;                 // 8 feats per lane
    for (int dl = grp; dl < BUCKW; dl += 32) {
        int c0 = cstart[dl], c1 = cstart[dl + 1];
        float acc[8] = {0.f,0.f,0.f,0.f,0.f,0.f,0.f,0.f};
        float den = 0.f;
        float s2n = s2l[dl];
        for (int cb = c0; cb < c1; cb += 8) {
            int my = cb + lane;
            float ex_l = 0.f; int s_l = 0;
            if (my < c1) {
                int pk = sorted[my];
                s_l = pk >> BUCK_SH;
                float x = s1[s_l] + s2n;
                x = (x > 0.f) ? x : LRELU_ALPHA * x;
                ex_l = expf(x);
            }
            int m = c1 - cb; if (m > 8) m = 8;
            int   sj[8]; float exj[8];
            #pragma unroll
            for (int j = 0; j < 8; ++j) {
                exj[j] = __shfl(ex_l, j, 8);
                sj[j]  = __shfl(s_l,  j, 8);
            }
            uint4 wv[8];
            #pragma unroll
            for (int j = 0; j < 8; ++j)
                if (j < m) wv[j] = *(const uint4*)&Whb[sj[j] * OUTF + jg];
            #pragma unroll
            for (int j = 0; j < 8; ++j) {
                if (j < m) {
                    float ex = exj[j];
                    den += ex;
                    acc[0] += ex * bf16lo(wv[j].x); acc[1] += ex * bf16hi(wv[j].x);
                    acc[2] += ex * bf16lo(wv[j].y); acc[3] += ex * bf16hi(wv[j].y);
                    acc[4] += ex * bf16lo(wv[j].z); acc[5] += ex * bf16hi(wv[j].z);
                    acc[6] += ex * bf16lo(wv[j].w); acc[7] += ex * bf16hi(wv[j].w);
                }
            }
        }
        if (dl < nd) {
            float inv = (c1 > c0) ? 1.f / den : 0.f;
            float o[8];
            #pragma unroll
            for (int j = 0; j < 8; ++j) {
                float v = acc[j] * inv;
                o[j] = (v > 0.f) ? v : expm1f(v);
            }
            float* op = &out[(dstbase + dl) * OUTF + jg];
            *(float4*)(op + 0) = make_float4(o[0], o[1], o[2], o[3]);
            *(float4*)(op + 4) = make_float4(o[4], o[5], o[6], o[7]);
        }
    }
}

extern "C" void kernel_launch(void* const* d_in, const int* in_sizes, int n_in,
                              void* d_out, int out_size, void* d_ws, size_t ws_size,
                              hipStream_t stream) {
    const float* h  = (const float*)d_in[0];
    const int*   ei = (const int*)d_in[1];    // [2, E]: first E = src, next E = dst
    const float* W  = (const float*)d_in[2];
    const float* a  = (const float*)d_in[3];
    const int* src = ei;
    const int* dst = ei + GE;

    float* ws = (float*)d_ws;
    float* s1 = ws;                                          // N
    float* s2 = s1 + GN;                                     // N
    unsigned short* Whb = (unsigned short*)(s2 + GN);        // N*64 bf16
    int* epacked = (int*)(Whb + (size_t)GN * OUTF);          // NB*CAP
    int* ccount  = epacked + (size_t)NB * CAP;               // NB
    float* out = (float*)d_out;

    hipMemsetAsync(ccount, 0, NB * sizeof(int), stream);     // 3 KB, capture-safe
    k_front<<<NB + NCH, 256, 0, stream>>>(h, W, a, src, dst, Whb, s1, s2,
                                          ccount, epacked);
    k_fgather<<<NB, 256, 0, stream>>>(ccount, epacked, s1, s2, Whb, out);
}